// Round 9
// baseline (305.639 us; speedup 1.0000x reference)
//
#include <hip/hip_runtime.h>

typedef unsigned short u16;
typedef __attribute__((ext_vector_type(8))) short bf16x8;
typedef __attribute__((ext_vector_type(4))) float f32x4;
typedef __attribute__((ext_vector_type(2))) float f32x2;

constexpr int N_ = 32768;
constexpr int H_ = 128;
constexpr int G_ = 1024;
constexpr int T_ = 2;

__device__ __forceinline__ float sigf(float x){
  float e = __builtin_amdgcn_exp2f(x * -1.44269504f);
  return __builtin_amdgcn_rcpf(1.0f + e);
}
// paired-rcp: 1/dx,1/dy = rcp(dx*dy)*{dy,dx} (1 quarter-rate rcp instead of 2).
__device__ __forceinline__ f32x2 sig2(f32x2 x){
  f32x2 t = x * -1.44269504f;
  f32x2 e; e.x = __builtin_amdgcn_exp2f(t.x); e.y = __builtin_amdgcn_exp2f(t.y);
  f32x2 d = e + 1.0f;
  float r = __builtin_amdgcn_rcpf(d.x * d.y);
  return (f32x2){r * d.y, r * d.x};
}
__device__ __forceinline__ f32x2 tanh2(f32x2 x){
  f32x2 t = x * 2.88539008f;
  f32x2 e; e.x = __builtin_amdgcn_exp2f(t.x); e.y = __builtin_amdgcn_exp2f(t.y);
  f32x2 d = e + 1.0f;
  float r = __builtin_amdgcn_rcpf(d.x * d.y);
  f32x2 rr = (f32x2){r * d.y, r * d.x};
  return 1.0f - 2.0f*rr;
}
__device__ __forceinline__ u16 f2bf(float f){
  unsigned u = __float_as_uint(f);
  unsigned r = (u + 0x7FFFu + ((u>>16)&1u))>>16;
  return (u16)r;
}
__device__ __forceinline__ unsigned cvt_pk_bf16(float a, float b){
  unsigned r;
  asm("v_cvt_pk_bf16_f32 %0, %1, %2" : "=v"(r) : "v"(a), "v"(b));
  return r;
}
__device__ __forceinline__ float bf2f(u16 h){ return __uint_as_float(((unsigned)h)<<16); }
__device__ __forceinline__ float asf(unsigned u){ return __uint_as_float(u); }
__device__ __forceinline__ f32x4 mfma16(bf16x8 a, bf16x8 b, f32x4 c){
  return __builtin_amdgcn_mfma_f32_16x16x32_bf16(a,b,c,0,0,0);
}

// ---------------- unified weight+bias pack (single launch, 417 blocks x 64) ----
// perm 1 (gate-block):       p = w*64+g*16+lc -> o = g*Fh+w*16+lc
// perm 2 (gate-interleaved): p = w*64+lc*4+g  -> o = g*Fh+w*16+lc
__global__ __launch_bounds__(64)
void pack_all(const float* __restrict__ l1Wih, const float* __restrict__ fcs1W,
              const float* __restrict__ l1Whh, const float* __restrict__ fcn1W,
              const float* __restrict__ l2Wih, const float* __restrict__ fcs2W,
              const float* __restrict__ l2Whh, const float* __restrict__ fcn2W,
              const float* __restrict__ l1b, const float* __restrict__ bs1,
              const float* __restrict__ bn1,
              const float* __restrict__ l2b, const float* __restrict__ bs2,
              const float* __restrict__ bn2,
              u16* BI1, u16* BW1, u16* BS1, u16* BN1,
              u16* BY2, u16* BW2, u16* BN2,
              u16* bG1, u16* bsn1, u16* bY2)
{
  int b = blockIdx.x;
  const int lane = threadIdx.x;
  if (b == 416) {                      // bias pack
    for (int i = lane; i < 1024; i += 64) {
      if (i < 256) {                   // layer-1 gate bias, gate-block perm
        int p = i;
        int o = ((p>>4)&3)*64 + ((p>>6)<<4) + (p&15);
        bG1[p] = f2bf(l1b[o]);
      } else if (i < 384) {            // layer-1 fc bias sum
        int j = i - 256;
        bsn1[j] = f2bf(bs1[j] + bn1[j]);
      } else {
        int p = i - 384; float v;
        if (p < 512) { int o = (p&3)*128 + ((p>>6)<<4) + ((p>>2)&15); v = l2b[o]; }
        else         { int j = p-512; v = bs2[j] + bn2[j]; }
        bY2[p] = f2bf(v);
      }
    }
    return;
  }
  const float* src; u16* dst; int srcNC, NTtot, ntOff, ntCnt, Fh, perm;
  if      (b < 32)  { src=l1Wih; dst=BI1; srcNC=256; NTtot=16; ntOff=0;  ntCnt=16; Fh=64;  perm=1; }
  else if (b < 64)  { src=l1Whh; dst=BW1; srcNC=256; NTtot=16; ntOff=0;  ntCnt=16; Fh=64;  perm=1; b-=32; }
  else if (b < 80)  { src=fcs1W; dst=BS1; srcNC=128; NTtot=8;  ntOff=0;  ntCnt=8;  Fh=0;   perm=0; b-=64; }
  else if (b < 96)  { src=fcn1W; dst=BN1; srcNC=128; NTtot=8;  ntOff=0;  ntCnt=8;  Fh=0;   perm=0; b-=80; }
  else if (b < 224) { src=l2Wih; dst=BY2; srcNC=512; NTtot=40; ntOff=0;  ntCnt=32; Fh=128; perm=2; b-=96; }
  else if (b < 256) { src=fcs2W; dst=BY2; srcNC=128; NTtot=40; ntOff=32; ntCnt=8;  Fh=0;   perm=0; b-=224; }
  else if (b < 384) { src=l2Whh; dst=BW2; srcNC=512; NTtot=32; ntOff=0;  ntCnt=32; Fh=128; perm=1; b-=256; }
  else              { src=fcn2W; dst=BN2; srcNC=128; NTtot=8;  ntOff=0;  ntCnt=8;  Fh=0;   perm=0; b-=384; }
  const int ntl = b % ntCnt, kt = b / ntCnt;
  const int n = lane & 15, qq = lane >> 4;
  int pr = ntl*16 + n;
  int o;
  if (perm == 1)      o = ((pr>>4)&3)*Fh + ((pr>>6)<<4) + (pr&15);
  else if (perm == 2) o = (pr&3)*Fh + ((pr>>6)<<4) + ((pr>>2)&15);
  else                o = pr;
  u16* d = dst + ((size_t)((kt*NTtot + ntOff + ntl)*64 + lane))*8;
#pragma unroll
  for (int j = 0; j < 8; ++j) {
    int k = kt*32 + qq*8 + j;
    d[j] = f2bf(src[(size_t)k*srcNC + o]);
  }
}

// ---------------- cast X fp32 -> bf16 (4 MB, L2-resident afterward) ----------
__global__ __launch_bounds__(256)
void cast_kernel(const float* __restrict__ X, u16* __restrict__ Xbf)
{
  int i = (blockIdx.x*256 + threadIdx.x)*8;
  float4 a = *(const float4*)(X + i);
  float4 b = *(const float4*)(X + i + 4);
  ushort4 r0, r1;
  r0.x=f2bf(a.x); r0.y=f2bf(a.y); r0.z=f2bf(a.z); r0.w=f2bf(a.w);
  r1.x=f2bf(b.x); r1.y=f2bf(b.y); r1.z=f2bf(b.z); r1.w=f2bf(b.w);
  *(ushort4*)(void*)(Xbf + i)     = r0;
  *(ushort4*)(void*)(Xbf + i + 4) = r1;
}

// ---------------- fully-fused layer 1 ----------------------------------------
// gates[16 x 256] = bias + Xn@Wih1 + h@Whh1 (both MFMA, weights in registers).
// Epilogue: h1 = sigmoid(x_self@Ws + h_K@Wn + bsn). No Y1 materialization.
__global__ __launch_bounds__(256, 4)
void lstm1_fused(const int* __restrict__ nbr, const u16* __restrict__ Xbf,
                 const u16* __restrict__ BI, const u16* __restrict__ BW,
                 const u16* __restrict__ BS, const u16* __restrict__ BNw,
                 const u16* __restrict__ bG, const u16* __restrict__ bsn,
                 u16* __restrict__ out)
{
  constexpr int STR = 72;              // bf16 elems per LDS row (64 + 8 pad)
  __shared__ __align__(16) u16 h_lds[2][16*STR];
  __shared__ __align__(16) u16 x_lds[2][16*STR];
  __shared__ int nbr_s[256];
  const int tid  = threadIdx.x;
  const int base = blockIdx.x * 16;
  const int lane = tid & 63, w = tid >> 6;
  const int lc = lane & 15, q = lane >> 4;

  nbr_s[tid] = nbr[base*16 + tid];

  bf16x8 bw[2][4], bx[2][4];
#pragma unroll
  for (int kt = 0; kt < 2; ++kt)
#pragma unroll
    for (int g = 0; g < 4; ++g) {
      bw[kt][g] = *(const bf16x8*)(const void*)(BW + ((size_t)((kt*16 + w*4 + g)*64 + lane))*8);
      bx[kt][g] = *(const bf16x8*)(const void*)(BI + ((size_t)((kt*16 + w*4 + g)*64 + lane))*8);
    }
  float b4[4];
#pragma unroll
  for (int g = 0; g < 4; ++g) b4[g] = bf2f(bG[w*64 + g*16 + lc]);

  f32x2 cs[2];
  cs[0] = (f32x2){0.f,0.f}; cs[1] = (f32x2){0.f,0.f};

  const int srow = tid >> 4, scol = tid & 15;  // staging: 16 threads/row, 8B each
  __syncthreads();                     // nbr_s visible
  {
    unsigned vr = (unsigned)nbr_s[srow*16 + 0];
    uint2 v = *(const uint2*)(const void*)((const char*)Xbf + (vr*128u + scol*8u));
    *(uint2*)(void*)((char*)&x_lds[0][0] + srow*144 + scol*8) = v;
  }
  __syncthreads();

  const int wcol = w*16 + lc;
  for (int t = 0; t < 16; ++t) {
    const u16* hr = h_lds[t & 1];
    const u16* xr = x_lds[t & 1];
    u16*       hw = h_lds[(t & 1) ^ 1];
    // prefetch next x-rows into regs (latency hidden over MFMA+pointwise)
    uint2 pv;
    if (t < 15) {
      unsigned vr = (unsigned)nbr_s[srow*16 + t + 1];
      pv = *(const uint2*)(const void*)((const char*)Xbf + (vr*128u + scol*8u));
    }
    f32x4 acc[4];
#pragma unroll
    for (int g = 0; g < 4; ++g)
#pragma unroll
      for (int r = 0; r < 4; ++r) acc[g][r] = b4[g];
#pragma unroll
    for (int kt = 0; kt < 2; ++kt) {
      bf16x8 af = *(const bf16x8*)(const void*)(xr + lc*STR + kt*32 + q*8);
#pragma unroll
      for (int g = 0; g < 4; ++g) acc[g] = mfma16(af, bx[kt][g], acc[g]);
    }
    if (t != 0) {
#pragma unroll
      for (int kt = 0; kt < 2; ++kt) {
        bf16x8 af = *(const bf16x8*)(const void*)(hr + lc*STR + kt*32 + q*8);
#pragma unroll
        for (int g = 0; g < 4; ++g) acc[g] = mfma16(af, bw[kt][g], acc[g]);
      }
    }
#pragma unroll
    for (int rp = 0; rp < 2; ++rp) {
      f32x2 gi = (f32x2){acc[0][2*rp], acc[0][2*rp+1]};
      f32x2 gf = (f32x2){acc[1][2*rp], acc[1][2*rp+1]};
      f32x2 gg = (f32x2){acc[2][2*rp], acc[2][2*rp+1]};
      f32x2 go = (f32x2){acc[3][2*rp], acc[3][2*rp+1]};
      f32x2 c  = sig2(gf)*cs[rp] + sig2(gi)*tanh2(gg);
      cs[rp] = c;
      f32x2 hh = sig2(go)*tanh2(c);
      unsigned pkd = cvt_pk_bf16(hh.x, hh.y);
      int r0 = q*4 + 2*rp;
      hw[r0*STR + wcol]     = (u16)pkd;
      hw[(r0+1)*STR + wcol] = (u16)(pkd >> 16);
    }
    if (t < 15)
      *(uint2*)(void*)((char*)&x_lds[(t & 1) ^ 1][0] + srow*144 + scol*8) = pv;
    __syncthreads();
  }

  // ---- epilogue: h1 = sigmoid(x_self@Ws + h_K@Wn + bsn) ----
  {
    uint2 v = *(const uint2*)(const void*)((const char*)Xbf + ((unsigned)(base + srow)*128u + scol*8u));
    *(uint2*)(void*)((char*)&x_lds[0][0] + srow*144 + scol*8) = v;
  }
  __syncthreads();
  const u16* hf = h_lds[0];            // t=15 wrote buffer 0
  const u16* xf = x_lds[0];
#pragma unroll
  for (int cc = 0; cc < 2; ++cc) {
    const int nt = w*2 + cc;
    const int col = nt*16 + lc;
    f32x4 a2;
    float bv = bf2f(bsn[col]);
#pragma unroll
    for (int r = 0; r < 4; ++r) a2[r] = bv;
#pragma unroll
    for (int kt = 0; kt < 2; ++kt) {
      bf16x8 sf = *(const bf16x8*)(const void*)(BS  + ((size_t)((kt*8 + nt)*64 + lane))*8);
      bf16x8 nf = *(const bf16x8*)(const void*)(BNw + ((size_t)((kt*8 + nt)*64 + lane))*8);
      bf16x8 ax = *(const bf16x8*)(const void*)(xf + lc*STR + kt*32 + q*8);
      bf16x8 ah = *(const bf16x8*)(const void*)(hf + lc*STR + kt*32 + q*8);
      a2 = mfma16(ax, sf, a2);
      a2 = mfma16(ah, nf, a2);
    }
#pragma unroll
    for (int r = 0; r < 4; ++r)
      out[(size_t)(base + q*4 + r)*H_ + col] = f2bf(sigf(a2[r]));
  }
}

// ---------------- MFMA GEMM (layer-2 Y): out = A@B + bias --------------------
template<int KT, int NTT, int AF32>
__global__ __launch_bounds__(256, 2)
void gemm_kernel(const void* __restrict__ Ain,
                 const u16* __restrict__ Bpk,
                 const u16* __restrict__ biasbf,
                 u16* __restrict__ out, int out_stride)
{
  constexpr int KA  = KT*32;
  constexpr int NTW = NTT/4;
  constexpr int STR = KA + 8;
  __shared__ __align__(16) u16 a_lds[32*STR];
  const int tid  = threadIdx.x;
  const int base = blockIdx.x*32;
  {
    const int sub = tid & 7, rowl = tid >> 3;
    if constexpr (AF32) {
      const float* src = (const float*)Ain + (size_t)(base+rowl)*KA;
#pragma unroll
      for (int cc = 0; cc < KA/32; ++cc) {
        int e0 = (cc*8+sub)*4;
        float4 v = *(const float4*)(src + e0);
        ushort4 bv;
        bv.x = f2bf(v.x); bv.y = f2bf(v.y); bv.z = f2bf(v.z); bv.w = f2bf(v.w);
        *(ushort4*)(void*)(a_lds + rowl*STR + e0) = bv;
      }
    } else {
      const u16* src = (const u16*)Ain + (size_t)(base+rowl)*KA;
#pragma unroll
      for (int cc = 0; cc < KA/64; ++cc) {
        int e0 = (cc*8+sub)*8;
        uint4 v = *(const uint4*)(const void*)(src + e0);
        *(uint4*)(void*)(a_lds + rowl*STR + e0) = v;
      }
    }
  }
  __syncthreads();
  const int lane = tid & 63, w = tid >> 6;
  const int lc = lane & 15, q = lane >> 4;
  f32x4 acc[2][NTW];
  f32x4 z = {0.f,0.f,0.f,0.f};
#pragma unroll
  for (int m = 0; m < 2; ++m)
#pragma unroll
    for (int j = 0; j < NTW; ++j) acc[m][j] = z;
#pragma unroll
  for (int kt = 0; kt < KT; ++kt) {
    bf16x8 af0 = *(const bf16x8*)(const void*)(a_lds + lc*STR      + kt*32 + q*8);
    bf16x8 af1 = *(const bf16x8*)(const void*)(a_lds + (lc+16)*STR + kt*32 + q*8);
#pragma unroll
    for (int j = 0; j < NTW; ++j) {
      bf16x8 bf = *(const bf16x8*)(const void*)(Bpk + ((size_t)((kt*NTT + w*NTW + j)*64 + lane))*8);
      acc[0][j] = mfma16(af0, bf, acc[0][j]);
      acc[1][j] = mfma16(af1, bf, acc[1][j]);
    }
  }
#pragma unroll
  for (int m = 0; m < 2; ++m)
#pragma unroll
    for (int j = 0; j < NTW; ++j) {
      int col = (w*NTW + j)*16 + lc;
#pragma unroll
      for (int r = 0; r < 4; ++r) {
        int row = base + m*16 + q*4 + r;
        out[(size_t)row*out_stride + col] = f2bf(acc[m][j][r] + bf2f(biasbf[col]));
      }
    }
}

// ---------------- LSTM layer 2 (R8 winner config, unchanged) ------------------
template<int KT, int MT, int MW>
__global__ __launch_bounds__(KT*128, MW)
void lstm_kernel(const int* __restrict__ nbr,
                 const u16* __restrict__ Y, int nctot,
                 const u16* __restrict__ Bpk,
                 const u16* __restrict__ BN,
                 const u16* __restrict__ Sp, int s_stride, int s_coloff,
                 u16* __restrict__ out)
{
  constexpr int F   = KT*32;
  constexpr int NW  = KT*2;
  constexpr int NTT = KT*8;
  constexpr int STR = F + 8;
  constexpr int M   = MT*16;
  __shared__ __align__(16) u16 h_lds[2][M*STR];
  __shared__ int nbr_s[M*16];
  const int tid  = threadIdx.x;
  const int base = blockIdx.x * M;
  const int lane = tid & 63, w = tid >> 6;
  const int lc = lane & 15, q = lane >> 4;

  for (int i = tid; i < M*16; i += NW*64) nbr_s[i] = nbr[base*16 + i];

  bf16x8 bfr[KT][4];
#pragma unroll
  for (int kt = 0; kt < KT; ++kt)
#pragma unroll
    for (int g = 0; g < 4; ++g)
      bfr[kt][g] = *(const bf16x8*)(const void*)(Bpk + ((size_t)((kt*NTT + w*4 + g)*64 + lane))*8);

  f32x2 cs[MT][2];
#pragma unroll
  for (int m = 0; m < MT; ++m)
#pragma unroll
    for (int rp = 0; rp < 2; ++rp) cs[m][rp] = (f32x2){0.f, 0.f};
  __syncthreads();

  const char* Yb = (const char*)Y;
  const unsigned rowbytes = (unsigned)nctot * 2u;
  const unsigned lanebyte = (unsigned)(w*64 + lc*4) * 2u;
  const int wcol = w*16 + lc;

  uint2 yv[MT][4];
#pragma unroll
  for (int m = 0; m < MT; ++m)
#pragma unroll
    for (int r = 0; r < 4; ++r) {
      unsigned vr = (unsigned)nbr_s[(m*16 + q*4 + r)*16];
      yv[m][r] = *(const uint2*)(const void*)(Yb + (vr*rowbytes + lanebyte));
    }

  for (int t = 0; t < 16; ++t) {
    const u16* hr = h_lds[t & 1];
    u16*       hw = h_lds[(t & 1) ^ 1];
#pragma unroll
    for (int m = 0; m < MT; ++m) {
      f32x4 acc[4];
      f32x4 z = {0.f,0.f,0.f,0.f};
#pragma unroll
      for (int g = 0; g < 4; ++g) acc[g] = z;
      if (t != 0) {
#pragma unroll
        for (int kt = 0; kt < KT; ++kt) {
          bf16x8 af = *(const bf16x8*)(const void*)(hr + (lc + m*16)*STR + kt*32 + q*8);
#pragma unroll
          for (int g = 0; g < 4; ++g) acc[g] = mfma16(af, bfr[kt][g], acc[g]);
        }
      }
#pragma unroll
      for (int rp = 0; rp < 2; ++rp) {
        uint2 ya = yv[m][2*rp], yb = yv[m][2*rp+1];
        f32x2 yi = { asf(ya.x<<16),          asf(yb.x<<16) };
        f32x2 yf = { asf(ya.x&0xffff0000u),  asf(yb.x&0xffff0000u) };
        f32x2 yg = { asf(ya.y<<16),          asf(yb.y<<16) };
        f32x2 yo = { asf(ya.y&0xffff0000u),  asf(yb.y&0xffff0000u) };
        f32x2 gi = (f32x2){acc[0][2*rp], acc[0][2*rp+1]} + yi;
        f32x2 gf = (f32x2){acc[1][2*rp], acc[1][2*rp+1]} + yf;
        f32x2 gg = (f32x2){acc[2][2*rp], acc[2][2*rp+1]} + yg;
        f32x2 go = (f32x2){acc[3][2*rp], acc[3][2*rp+1]} + yo;
        f32x2 c  = sig2(gf)*cs[m][rp] + sig2(gi)*tanh2(gg);
        cs[m][rp] = c;
        f32x2 hh = sig2(go)*tanh2(c);
        unsigned pkd = cvt_pk_bf16(hh.x, hh.y);
        int r0 = m*16 + q*4 + 2*rp;
        hw[r0*STR + wcol]     = (u16)pkd;
        hw[(r0+1)*STR + wcol] = (u16)(pkd >> 16);
      }
    }
    if (t < 15) {
#pragma unroll
      for (int m = 0; m < MT; ++m)
#pragma unroll
        for (int r = 0; r < 4; ++r) {
          unsigned vr = (unsigned)nbr_s[(m*16 + q*4 + r)*16 + t + 1];
          yv[m][r] = *(const uint2*)(const void*)(Yb + (vr*rowbytes + lanebyte));
        }
    }
    __syncthreads();
  }

  // ---- fused fc_neigh + sigmoid epilogue (h_K in h_lds[0]) ----
  constexpr int CPW = 8 / NW;
  const u16* hf = h_lds[0];
#pragma unroll
  for (int cc2 = 0; cc2 < CPW; ++cc2) {
    const int nt = w*CPW + cc2;
    f32x4 a2[MT];
    f32x4 z = {0.f,0.f,0.f,0.f};
#pragma unroll
    for (int m = 0; m < MT; ++m) a2[m] = z;
#pragma unroll
    for (int kt = 0; kt < KT; ++kt) {
      bf16x8 nf = *(const bf16x8*)(const void*)(BN + ((size_t)((kt*8 + nt)*64 + lane))*8);
#pragma unroll
      for (int m = 0; m < MT; ++m) {
        bf16x8 af = *(const bf16x8*)(const void*)(hf + (lc + m*16)*STR + kt*32 + q*8);
        a2[m] = mfma16(af, nf, a2[m]);
      }
    }
    const int col = nt*16 + lc;
#pragma unroll
    for (int m = 0; m < MT; ++m)
#pragma unroll
      for (int r = 0; r < 4; ++r) {
        int row = base + m*16 + q*4 + r;
        float v = a2[m][r] + bf2f(Sp[(size_t)row*s_stride + s_coloff + col]);
        out[(size_t)row*H_ + col] = f2bf(sigf(v));
      }
  }
}

// ---------------- readout + head (graphs = 32 contiguous nodes) --------------
__global__ __launch_bounds__(128)
void head_kernel(const u16* __restrict__ h2, const float* __restrict__ rwW,
                 const float* __restrict__ rwb,
                 const float* __restrict__ h1W, const float* __restrict__ h1b,
                 const float* __restrict__ h2W, const float* __restrict__ h2b,
                 float* __restrict__ out)
{
  __shared__ float h2s[32*H_];
  __shared__ float part[32*4];
  __shared__ float wv[32];
  __shared__ float gemb[2*H_];
  __shared__ float y1[H_];
  const int g = blockIdx.x, t = threadIdx.x;
  for (int r = 0; r < 32; ++r)
    h2s[r*H_ + t] = bf2f(h2[(size_t)(g*32 + r)*H_ + t]);
  __syncthreads();
  { int r = t>>2, qq = t&3; float p = 0.f;
    for (int h = qq*32; h < qq*32+32; ++h) p += h2s[r*H_+h]*rwW[h];
    part[r*4+qq] = p; }
  __syncthreads();
  if (t < 32) wv[t] = sigf(part[t*4]+part[t*4+1]+part[t*4+2]+part[t*4+3]+rwb[0]);
  __syncthreads();
  { float wsum=0.f, mx=-3.402823466e38f;
    for (int r = 0; r < 32; ++r) { float v = h2s[r*H_+t]; wsum += wv[r]*v; mx = fmaxf(mx,v); }
    gemb[t]=wsum; gemb[H_+t]=mx; }
  __syncthreads();
  { float a = h1b[t];
    for (int k = 0; k < 2*H_; ++k) a += gemb[k]*h1W[k*H_+t];
    y1[t]=sigf(a); }
  __syncthreads();
  if (t < T_) {
    float a = h2b[t];
    for (int h = 0; h < H_; ++h) a += y1[h]*h2W[h*T_+t];
    out[(size_t)g*T_+t] = sigf(a);
  }
}

extern "C" void kernel_launch(void* const* d_in, const int* in_sizes, int n_in,
                              void* d_out, int out_size, void* d_ws, size_t ws_size,
                              hipStream_t stream) {
  const float* n_feat = (const float*)d_in[0];
  const int*   nbr    = (const int*)d_in[1];
  const float* l1Wih = (const float*)d_in[4];
  const float* l1Whh = (const float*)d_in[5];
  const float* l1b   = (const float*)d_in[6];
  const float* fcs1W = (const float*)d_in[7];
  const float* fcs1b = (const float*)d_in[8];
  const float* fcn1W = (const float*)d_in[9];
  const float* fcn1b = (const float*)d_in[10];
  const float* l2Wih = (const float*)d_in[11];
  const float* l2Whh = (const float*)d_in[12];
  const float* l2b   = (const float*)d_in[13];
  const float* fcs2W = (const float*)d_in[14];
  const float* fcs2b = (const float*)d_in[15];
  const float* fcn2W = (const float*)d_in[16];
  const float* fcn2b = (const float*)d_in[17];
  const float* rwW   = (const float*)d_in[18];
  const float* rwb   = (const float*)d_in[19];
  const float* h1W   = (const float*)d_in[20];
  const float* h1b   = (const float*)d_in[21];
  const float* h2W   = (const float*)d_in[22];
  const float* h2b   = (const float*)d_in[23];

  char* ws = (char*)d_ws;
  u16* Y   = (u16*)(ws);                         // [N x 640] layer-2 gates, 40 MB
  u16* Xbf = (u16*)(ws + 41943040);              // [N x 64] bf16, 4 MB
  u16* h1  = (u16*)(ws + 46137344);              // [N x 128] bf16
  u16* h2  = (u16*)(ws + 54525952);              // [N x 128] bf16
  char* wt = ws + 62914560;
  u16* BI1  = (u16*)(wt);                        // Wih1 perm1, 32 KB
  u16* BW1  = (u16*)(wt + 32768);                // Whh1 perm1, 32 KB
  u16* BS1  = (u16*)(wt + 65536);                // fcs1W, 16 KB
  u16* BN1  = (u16*)(wt + 81920);                // fcn1W, 16 KB
  u16* BY2  = (u16*)(wt + 98304);                // [Wih2 perm2 | fcs2W], 160 KB
  u16* BW2  = (u16*)(wt + 262144);               // Whh2 perm1, 128 KB
  u16* BN2  = (u16*)(wt + 393216);               // fcn2W, 32 KB
  u16* bG1  = (u16*)(wt + 425984);               // 256 gate biases perm1
  u16* bsn1 = (u16*)(wt + 426496);               // 128 bs1+bn1
  u16* bY2  = (u16*)(wt + 426752);               // 640

  pack_all<<<417, 64, 0, stream>>>(l1Wih, fcs1W, l1Whh, fcn1W,
                                   l2Wih, fcs2W, l2Whh, fcn2W,
                                   l1b, fcs1b, fcn1b, l2b, fcs2b, fcn2b,
                                   BI1, BW1, BS1, BN1, BY2, BW2, BN2,
                                   bG1, bsn1, bY2);

  cast_kernel<<<1024, 256, 0, stream>>>(n_feat, Xbf);
  lstm1_fused<<<2048, 256, 0, stream>>>(nbr, Xbf, BI1, BW1, BS1, BN1, bG1, bsn1, h1);

  gemm_kernel<4,40,0><<<1024, 256, 0, stream>>>(h1, BY2, bY2, Y, 640);
  lstm_kernel<4,1,4><<<2048, 512, 0, stream>>>(nbr, Y, 640, BW2, BN2, Y, 640, 512, h2);

  head_kernel<<<G_, 128, 0, stream>>>(h2, rwW, rwb, h1W, h1b, h2W, h2b, (float*)d_out);
}